// Round 3
// baseline (423.298 us; speedup 1.0000x reference)
//
#include <hip/hip_runtime.h>

// HeavySnow: stamp flakes (0.95 squares, all channels) -> depthwise 5x5
// gaussian blur (zero pad) -> clip [0,1].
// R5: barrier-free register sliding-window blur. No LDS, no __syncthreads.
// Each wave owns a 256-px strip (lane = one float4 word); 5 rotating vertical
// accumulators (full unroll -> registers); 2-deep load prefetch; horizontal
// halo via __shfl, wave-edge word via predicated float2 halo pipe (lanes 0/63).
// Flake substitution inline from mask dwords (L2-resident).

#define H_ 1024
#define W_ 1024
#define B_ 16
#define C_ 3
#define NF_ 15728
#define MASK_WORDS_PER_B (H_ * W_ / 32)  // 32768 words (128 KB) per batch

// Gaussian weights: sigma=1.5, K=5, normalized. g = [g0,g1,g2,g1,g0].
#define G0 0.12007838f
#define G1 0.23388076f
#define G2 0.29208172f

__global__ void clear_mask_kernel(uint4* __restrict__ mask, int n4) {
    int i = blockIdx.x * blockDim.x + threadIdx.x;
    if (i < n4) mask[i] = make_uint4(0u, 0u, 0u, 0u);
}

__global__ void stamp_kernel(const int* __restrict__ ys, const int* __restrict__ xs,
                             const int* __restrict__ rs, unsigned int* __restrict__ mask) {
    int t = blockIdx.x * blockDim.x + threadIdx.x;
    if (t >= B_ * NF_) return;
    int b = t / NF_;
    int y0 = ys[t], x0 = xs[t], r = rs[t];
    unsigned int* mb = mask + b * MASK_WORDS_PER_B;
    int xlo = max(x0 - r, 0), xhi = min(x0 + r, W_ - 1);
    int ylo = max(y0 - r, 0), yhi = min(y0 + r, H_ - 1);
    for (int y = ylo; y <= yhi; ++y) {
        int i0 = (y << 10) + xlo;
        int i1 = (y << 10) + xhi;
        int w0 = i0 >> 5, w1 = i1 >> 5;
        unsigned int m0 = ~0u << (i0 & 31);
        unsigned int m1 = ~0u >> (31 - (i1 & 31));
        if (w0 == w1) {
            atomicOr(mb + w0, m0 & m1);
        } else {
            atomicOr(mb + w0, m0);
            atomicOr(mb + w1, m1);
        }
    }
}

constexpr int BAND = 32;           // output rows per block
constexpr int NITER = BAND + 4;    // raw rows consumed per band

__global__ __launch_bounds__(256, 4) void blur_kernel(const float* __restrict__ x,
                                                      const unsigned int* __restrict__ mask,
                                                      float* __restrict__ out) {
    const int plane = blockIdx.z;          // b*C + c
    const int b = plane / C_;
    const float* xp = x + (size_t)plane * (H_ * W_);
    float* op = out + (size_t)plane * (H_ * W_);
    const unsigned int* mb = mask + b * MASK_WORDS_PER_B;

    const int tid = threadIdx.x;
    const int wv = tid >> 6;               // wave id 0..3 -> strip
    const int ln = tid & 63;               // lane -> float4 word in strip
    const int gx4 = (wv << 8) + (ln << 2); // scalar col of this lane's word
    const int y0 = blockIdx.y * BAND;

    const bool isL = (ln == 0), isR = (ln == 63);
    // Halo float2: L lane needs scalars gx4-2,gx4-1; R lane needs gx4+4,gx4+5.
    const int hoff = isL ? gx4 - 2 : gx4 + 4;
    const bool haloOn = (isL || isR) && ((unsigned)hoff < (unsigned)W_);
    const int mwi = gx4 >> 5, mbit = gx4 & 31;
    const int hwi = hoff >> 5, hbit = hoff & 31;

    float4 acc[5];                         // rotating vertical accumulators
    float2 hacc[5];                        // halo accumulators (lanes 0/63)
    #pragma unroll
    for (int s = 0; s < 5; ++s) {
        acc[s] = make_float4(0.f, 0.f, 0.f, 0.f);
        hacc[s] = make_float2(0.f, 0.f);
    }

    float4 px[2];  unsigned int pm[2];     // 2-deep main prefetch
    float2 ph[2];  unsigned int phm[2];    // 2-deep halo prefetch
    px[0] = px[1] = make_float4(0.f, 0.f, 0.f, 0.f);
    ph[0] = ph[1] = make_float2(0.f, 0.f);
    pm[0] = pm[1] = 0u; phm[0] = phm[1] = 0u;

    auto load_row = [&](int i, float4& vx, unsigned int& vm,
                        float2& vh, unsigned int& vhm) {
        int gy = y0 - 2 + i;
        if ((unsigned)gy < (unsigned)H_) {
            vx = *(const float4*)(xp + (gy << 10) + gx4);
            vm = mb[(gy << 5) + mwi];
            if (haloOn) {
                vh = *(const float2*)(xp + (gy << 10) + hoff);
                vhm = mb[(gy << 5) + hwi];
            } else { vh = make_float2(0.f, 0.f); vhm = 0u; }
        } else {
            vx = make_float4(0.f, 0.f, 0.f, 0.f); vm = 0u;
            vh = make_float2(0.f, 0.f); vhm = 0u;
        }
    };

    load_row(0, px[0], pm[0], ph[0], phm[0]);
    load_row(1, px[1], pm[1], ph[1], phm[1]);

    #pragma unroll
    for (int i = 0; i < NITER; ++i) {
        // consume pending row (raw row gy = y0-2+i), flake substitution
        float4 vr = px[i & 1];
        unsigned int m = pm[i & 1];
        if ((m >> (mbit + 0)) & 1u) vr.x = 0.95f;
        if ((m >> (mbit + 1)) & 1u) vr.y = 0.95f;
        if ((m >> (mbit + 2)) & 1u) vr.z = 0.95f;
        if ((m >> (mbit + 3)) & 1u) vr.w = 0.95f;
        float2 hr = ph[i & 1];
        unsigned int hm = phm[i & 1];
        if ((hm >> (hbit + 0)) & 1u) hr.x = 0.95f;
        if ((hm >> (hbit + 1)) & 1u) hr.y = 0.95f;

        // refill prefetch slot with row i+2
        if (i + 2 < NITER) load_row(i + 2, px[i & 1], pm[i & 1], ph[i & 1], phm[i & 1]);

        // vertical accumulation into up to 5 rotating accumulators
        #pragma unroll
        for (int d = -2; d <= 2; ++d) {
            int ti = i - 2 + d;            // target output row index in band
            if (ti < 0 || ti >= BAND) continue;
            const float wk = (d == -2 || d == 2) ? G0 : ((d == -1 || d == 1) ? G1 : G2);
            const int sl = ti % 5;
            acc[sl].x += wk * vr.x; acc[sl].y += wk * vr.y;
            acc[sl].z += wk * vr.z; acc[sl].w += wk * vr.w;
            hacc[sl].x += wk * hr.x; hacc[sl].y += wk * hr.y;
        }

        // finish output row ti = i-4 (all 5 contributions in)
        if (i >= 4) {
            const int ti = i - 4;
            const int sl = ti % 5;
            float4 vb = acc[sl];
            float2 hvb = hacc[sl];
            float az = __shfl_up(vb.z, 1u);    // v[4l-2] from lane l-1
            float aw = __shfl_up(vb.w, 1u);    // v[4l-1]
            float cx = __shfl_down(vb.x, 1u);  // v[4l+4] from lane l+1
            float cy = __shfl_down(vb.y, 1u);  // v[4l+5]
            az = isL ? hvb.x : az;  aw = isL ? hvb.y : aw;
            cx = isR ? hvb.x : cx;  cy = isR ? hvb.y : cy;
            float4 o;
            o.x = G0 * (az + vb.z) + G1 * (aw + vb.y) + G2 * vb.x;
            o.y = G0 * (aw + vb.w) + G1 * (vb.x + vb.z) + G2 * vb.y;
            o.z = G0 * (vb.x + cx) + G1 * (vb.y + vb.w) + G2 * vb.z;
            o.w = G0 * (vb.y + cy) + G1 * (vb.z + cx) + G2 * vb.w;
            o.x = fminf(fmaxf(o.x, 0.0f), 1.0f);
            o.y = fminf(fmaxf(o.y, 0.0f), 1.0f);
            o.z = fminf(fmaxf(o.z, 0.0f), 1.0f);
            o.w = fminf(fmaxf(o.w, 0.0f), 1.0f);
            *(float4*)(op + ((y0 + ti) << 10) + gx4) = o;
            acc[sl] = make_float4(0.f, 0.f, 0.f, 0.f);
            hacc[sl] = make_float2(0.f, 0.f);
        }
    }
}

extern "C" void kernel_launch(void* const* d_in, const int* in_sizes, int n_in,
                              void* d_out, int out_size, void* d_ws, size_t ws_size,
                              hipStream_t stream) {
    const float* x  = (const float*)d_in[0];
    const int*   ys = (const int*)d_in[1];
    const int*   xs = (const int*)d_in[2];
    const int*   rs = (const int*)d_in[3];
    float* out = (float*)d_out;
    unsigned int* mask = (unsigned int*)d_ws;  // 16 * 32768 words = 2 MB

    int n4 = B_ * MASK_WORDS_PER_B / 4;
    clear_mask_kernel<<<dim3((n4 + 255) / 256), dim3(256), 0, stream>>>((uint4*)mask, n4);

    int nst = B_ * NF_;
    stamp_kernel<<<dim3((nst + 255) / 256), dim3(256), 0, stream>>>(ys, xs, rs, mask);

    dim3 grid(1, H_ / BAND, B_ * C_);
    blur_kernel<<<grid, dim3(256), 0, stream>>>(x, mask, out);
}